// Round 2
// 348.660 us; speedup vs baseline: 1.0148x; 1.0148x over previous
//
#include <hip/hip_runtime.h>

#define NDIM 8192
#define ROWS_PER_BLOCK 4
#define BLOCK 256
#define GRID (NDIM / ROWS_PER_BLOCK)   // 2048 blocks
#define CPT 8                          // cols per thread per tile (2 x float4)
#define TILE_STRIDE (BLOCK * CPT)      // 2048 cols per block-iteration
#define NITER (NDIM / TILE_STRIDE)     // 4 tiles per thread (compile-time)

typedef float fx4 __attribute__((ext_vector_type(4)));   // native vector: OK for nontemporal builtin

__global__ __launch_bounds__(BLOCK) void stress_partial_kernel(
    const float* __restrict__ pos,
    const float* __restrict__ dist,
    float* __restrict__ partials)
{
    const int row0 = blockIdx.x * ROWS_PER_BLOCK;
    const int jb0  = threadIdx.x * CPT;

    // block-uniform row positions (compiler scalarizes; cached)
    float pix[ROWS_PER_BLOCK], piy[ROWS_PER_BLOCK];
#pragma unroll
    for (int r = 0; r < ROWS_PER_BLOCK; ++r) {
        pix[r] = pos[2 * (row0 + r)];
        piy[r] = pos[2 * (row0 + r) + 1];
    }

    float accr[ROWS_PER_BLOCK] = {0.0f, 0.0f, 0.0f, 0.0f};

    // two named register buffers (no runtime indexing -> stays in VGPRs)
    fx4 dA[ROWS_PER_BLOCK][2], dB[ROWS_PER_BLOCK][2];
    fx4 pA[4], pB[4];

    auto LOAD = [&](int it, fx4 (&dreg)[ROWS_PER_BLOCK][2], fx4 (&preg)[4]) {
        const int jb = jb0 + it * TILE_STRIDE;
#pragma unroll
        for (int q = 0; q < 4; ++q)
            preg[q] = *(const fx4*)(pos + 2 * jb + 4 * q);
#pragma unroll
        for (int r = 0; r < ROWS_PER_BLOCK; ++r) {
            const fx4* drow =
                (const fx4*)(dist + (size_t)(row0 + r) * NDIM + jb);
            // dist is streamed exactly once: non-temporal, don't thrash L2/L3
            dreg[r][0] = __builtin_nontemporal_load(drow);
            dreg[r][1] = __builtin_nontemporal_load(drow + 1);
        }
    };

    auto COMPUTE = [&](const fx4 (&dreg)[ROWS_PER_BLOCK][2],
                       const fx4 (&preg)[4]) {
        float pjx[CPT], pjy[CPT];
#pragma unroll
        for (int q = 0; q < 4; ++q) {
            pjx[2 * q]     = preg[q].x;  pjy[2 * q]     = preg[q].y;
            pjx[2 * q + 1] = preg[q].z;  pjy[2 * q + 1] = preg[q].w;
        }
#pragma unroll
        for (int r = 0; r < ROWS_PER_BLOCK; ++r) {
            const float dv[CPT] = {dreg[r][0].x, dreg[r][0].y,
                                   dreg[r][0].z, dreg[r][0].w,
                                   dreg[r][1].x, dreg[r][1].y,
                                   dreg[r][1].z, dreg[r][1].w};
#pragma unroll
            for (int k = 0; k < CPT; ++k) {
                const float dx = pjx[k] - pix[r];
                const float dy = pjy[k] - piy[r];
                const float sq = __builtin_fmaf(dx, dx, dy * dy);
                // raw v_sqrt_f32 (1 instr, sqrt(0)=0 keeps the diagonal guard)
                const float pred = __builtin_amdgcn_sqrtf(sq);
                const float d = dv[k];
                const float t =
                    __builtin_fmaf(pred, __builtin_amdgcn_rcpf(d), -1.0f);
                const float z = (d != 0.0f) ? t : 0.0f;   // dist==0 term -> 0
                accr[r] = __builtin_fmaf(z, z, accr[r]);
            }
        }
    };

    // fully-unrolled 4-tile schedule, 1-deep register prefetch:
    // next tile's 12 loads are in flight while current tile computes.
    LOAD(0, dA, pA);
    LOAD(1, dB, pB);
    COMPUTE(dA, pA);
    LOAD(2, dA, pA);
    COMPUTE(dB, pB);
    LOAD(3, dB, pB);
    COMPUTE(dA, pA);
    COMPUTE(dB, pB);

    float acc = (accr[0] + accr[1]) + (accr[2] + accr[3]);

    // wave64 shuffle reduce
#pragma unroll
    for (int off = 32; off > 0; off >>= 1)
        acc += __shfl_down(acc, off, 64);

    __shared__ float wave_sums[BLOCK / 64];
    const int lane = threadIdx.x & 63;
    const int wave = threadIdx.x >> 6;
    if (lane == 0) wave_sums[wave] = acc;
    __syncthreads();

    if (threadIdx.x == 0) {
        float s = 0.0f;
#pragma unroll
        for (int w = 0; w < BLOCK / 64; ++w) s += wave_sums[w];
        partials[blockIdx.x] = s;   // overwrite: no zero-init needed
    }
}

__global__ __launch_bounds__(BLOCK) void reduce_final_kernel(
    const float* __restrict__ partials,
    float* __restrict__ out)
{
    float acc = 0.0f;
#pragma unroll
    for (int i = 0; i < GRID / BLOCK; ++i)          // 2048/256 = 8 per thread
        acc += partials[threadIdx.x + i * BLOCK];

#pragma unroll
    for (int off = 32; off > 0; off >>= 1)
        acc += __shfl_down(acc, off, 64);

    __shared__ float wave_sums[BLOCK / 64];
    const int lane = threadIdx.x & 63;
    const int wave = threadIdx.x >> 6;
    if (lane == 0) wave_sums[wave] = acc;
    __syncthreads();

    if (threadIdx.x == 0) {
        float s = 0.0f;
#pragma unroll
        for (int w = 0; w < BLOCK / 64; ++w) s += wave_sums[w];
        out[0] = s;                  // direct write: no memset node needed
    }
}

extern "C" void kernel_launch(void* const* d_in, const int* in_sizes, int n_in,
                              void* d_out, int out_size, void* d_ws, size_t ws_size,
                              hipStream_t stream)
{
    const float* pos  = (const float*)d_in[0];
    const float* dist = (const float*)d_in[1];
    float* out = (float*)d_out;
    float* partials = (float*)d_ws;

    stress_partial_kernel<<<GRID, BLOCK, 0, stream>>>(pos, dist, partials);
    reduce_final_kernel<<<1, BLOCK, 0, stream>>>(partials, out);
}